// Round 1
// 530.847 us; speedup vs baseline: 1.2337x; 1.2337x over previous
//
#include <hip/hip_runtime.h>
#include <hip/hip_bf16.h>

typedef unsigned short u16;
typedef unsigned int u32;
typedef __attribute__((ext_vector_type(8))) __bf16 bf8v;   // MFMA A/B operand
typedef __attribute__((ext_vector_type(4))) float f32x4;   // MFMA C/D

#define MFMA16(a, b, c) __builtin_amdgcn_mfma_f32_16x16x32_bf16((a), (b), (c), 0, 0, 0)

__device__ __forceinline__ float bf2f(u16 h){
  union { u32 u; float f; } v; v.u = ((u32)h) << 16; return v.f;
}
__device__ __forceinline__ u16 f2bf(float f){
  union { float f; u32 u; } v; v.f = f;
  u32 u = v.u;
  return (u16)((u + 0x7FFFu + ((u >> 16) & 1u)) >> 16);
}
__device__ __forceinline__ bf8v bneg(bf8v v){
  union { bf8v b; u16 u[8]; } a; a.b = v;
#pragma unroll
  for (int j = 0; j < 8; ++j) a.u[j] ^= 0x8000u;
  return a.b;
}

// ---- workspace layout (u16 element offsets); bf16 intermediates ----
static const size_t OFF_G   = 0;
static const size_t OFF_WY  = 33554432;
static const size_t OFF_WX  = 37748736;
static const size_t OFF_XY  = 41943040;
static const size_t OFF_XX  = 50331648;
static const size_t OFF_PQY = 58720256;
static const size_t OFF_PQX = 67108864;
static const size_t OFF_EY  = 75497472;
static const size_t OFF_EX  = OFF_EY + 16384;
static const size_t OFF_BY  = OFF_EX + 16384;
static const size_t OFF_BX  = OFF_BY + 16384;
static const size_t OFF_W1T = OFF_BX + 16384;
static const size_t OFF_W2T = OFF_W1T + 16384;

// ---------------- K0: mixing weights  W[b][y][c][o][i] = sum_k att[b][k]*fw[k][i][o][y][c]
__global__ __launch_bounds__(256)
void k_weights(const float* __restrict__ att, const float* __restrict__ fwy,
               const float* __restrict__ fwx, u16* __restrict__ Wy, u16* __restrict__ Wx){
  int blk = blockIdx.x;                 // 512 blocks: branch*256 + b*32 + y
  int branch = blk >> 8; int rem = blk & 255; int b = rem >> 5, y = rem & 31;
  const float* fw = branch ? fwx : fwy;
  u16* W = branch ? Wx : Wy;
  float ak[4];
#pragma unroll
  for (int k = 0; k < 4; ++k) ak[k] = att[b * 4 + k];
  __shared__ u16 Wt[2][64][72];
  int t = threadIdx.x;
  int o = t >> 2, i0 = (t & 3) << 4;
  for (int j = 0; j < 16; ++j){
    int i = i0 + j;
    float s0 = 0.f, s1 = 0.f;
#pragma unroll
    for (int k = 0; k < 4; ++k){
      float2 v = *(const float2*)(fw + ((((size_t)((k * 64 + i) * 64 + o)) * 32 + y) << 1));
      s0 += ak[k] * v.x;
      s1 += ak[k] * v.y;
    }
    Wt[0][o][i] = f2bf(s0);
    Wt[1][o][i] = f2bf(s1);
  }
  __syncthreads();
  {
    int c = t >> 7, oo = (t >> 1) & 63, ih = (t & 1) << 5;
    u16* dst = W + ((((size_t)(b * 32 + y)) * 2 + c) << 12) + (oo << 6) + ih;
    const u16* src = &Wt[c][oo][ih];
    uint4 v0 = *(const uint4*)(src);
    uint4 v1 = *(const uint4*)(src + 8);
    uint4 v2 = *(const uint4*)(src + 16);
    uint4 v3 = *(const uint4*)(src + 24);
    *(uint4*)(dst) = v0; *(uint4*)(dst + 8) = v1;
    *(uint4*)(dst + 16) = v2; *(uint4*)(dst + 24) = v3;
  }
}

// ---------------- K0b: basis matrices + weight transposes (fp32 -> bf16)
__global__ __launch_bounds__(256)
void k_basis(u16* __restrict__ Ey, u16* __restrict__ Ex,
             u16* __restrict__ By, u16* __restrict__ Bx,
             const float* __restrict__ w1, const float* __restrict__ w2,
             u16* __restrict__ w1T, u16* __restrict__ w2T){
  int idx = blockIdx.x * 256 + threadIdx.x;   // grid 64 -> idx < 16384
  const float C256 = 0.0245436926066f;  // 2*pi/256
  const float C510 = 0.0123199711905f;  // 2*pi/510
  {
    int u = idx >> 8, n = idx & 255;
    int y = u & 31;
    float ang = C256 * (float)((n * y) & 255);
    float v = (u < 32) ? cosf(ang) : -sinf(ang);
    Ey[idx] = f2bf(v);
    float vx;
    if (u < 32) vx = (n == 0) ? 1.f : (n == 255 ? ((u & 1) ? -1.f : 1.f) : 0.f);
    else        vx = -2.f * sinf(C510 * (float)((n * y) % 510));
    Ex[idx] = f2bf(vx);
  }
  {
    int n = idx >> 6, u = idx & 63;
    int y = u & 31;
    float ang = C256 * (float)((n * y) & 255);
    float v;
    if (u == 0)       v = 0.00390625f;                // 1/256
    else if (u < 32)  v = 0.0078125f * cosf(ang);     // 2/256 cos
    else if (u == 32) v = 0.f;                        // Im(F0) dropped by irfft
    else              v = -0.0078125f * sinf(ang);
    By[idx] = f2bf(v);
    float angx = C510 * (float)((n * y) % 510);
    float vx;
    if (u == 0)       vx = 1.f / 510.f;
    else if (u < 32)  vx = (2.f / 510.f) * cosf(angx);
    else if (u == 32) vx = 0.f;
    else              vx = -(2.f / 510.f) * sinf(angx);
    Bx[idx] = f2bf(vx);
  }
  {
    int k = idx >> 8, c = idx & 255;      // w1 (64,256)
    w1T[c * 64 + k] = f2bf(w1[idx]);
    int k2 = idx >> 6, o = idx & 63;      // w2 (256,64)
    w2T[o * 256 + k2] = f2bf(w2[idx]);
  }
}

// ---------------- K1/K3: forward transform.  D(64u x 64i) = E(64x256) @ xslice(256x64)
#define SWZ(i) ((((i) >> 3) & 7) << 3)
__global__ __launch_bounds__(256)
void k_fwd(const float* __restrict__ xin, const u16* __restrict__ E,
           u16* __restrict__ Xout, int mode){
  int blk = blockIdx.x; int b = blk >> 8, s = blk & 255;
  const float* xbase; size_t rstride;
  if (mode == 0){ xbase = xin + ((size_t)blk << 14); rstride = 64; }       // rows = n
  else          { xbase = xin + ((size_t)b << 22) + ((size_t)s << 6); rstride = 16384; } // rows = m
  __shared__ u16 xs[64][264];   // [i][row^swizzle]
  int t = threadIdx.x;
  {
    int r0 = t >> 4, i0 = (t & 15) << 2;
    int sw = SWZ(i0);
    for (int it = 0; it < 16; ++it){
      int r = r0 + (it << 4);
      float4 v = *(const float4*)(xbase + (size_t)r * rstride + i0);
      int rs = r ^ sw;
      xs[i0 + 0][rs] = f2bf(v.x);
      xs[i0 + 1][rs] = f2bf(v.y);
      xs[i0 + 2][rs] = f2bf(v.z);
      xs[i0 + 3][rs] = f2bf(v.w);
    }
  }
  __syncthreads();
  int wave = t >> 6, lane = t & 63, quad = lane >> 4, l15 = lane & 15;
  int urow = (wave << 4) + l15;
  f32x4 z = {0.f, 0.f, 0.f, 0.f};
  f32x4 acc[4] = {z, z, z, z};
  for (int k0 = 0; k0 < 256; k0 += 32){
    bf8v a = *(const bf8v*)(E + (urow << 8) + k0 + (quad << 3));
#pragma unroll
    for (int ct = 0; ct < 4; ++ct){
      int i = (ct << 4) + l15;
      bf8v bb = *(const bf8v*)(&xs[i][(k0 + (quad << 3)) ^ SWZ(i)]);
      acc[ct] = MFMA16(a, bb, acc[ct]);
    }
  }
#pragma unroll
  for (int ct = 0; ct < 4; ++ct)
#pragma unroll
    for (int r = 0; r < 4; ++r){
      int u = (wave << 4) + (quad << 2) + r;
      int col = (ct << 4) + l15;
      Xout[(((size_t)b * 64 + u) << 14) + (s << 6) + col] = f2bf(acc[ct][r]);
    }
}

// ---------------- K2/K4: mode mixing. per (b,y,half): P=Xr@Wr-Xi@Wi, Q=Xr@Wi+Xi@Wr
__global__ __launch_bounds__(256)
void k_mix(const u16* __restrict__ X, const u16* __restrict__ W, u16* __restrict__ PQ){
  int blk = blockIdx.x;           // 512: ((b*32+y)*2 + half)
  int half = blk & 1, by = blk >> 1, b = by >> 5, y = by & 31;
  int t = threadIdx.x, wave = t >> 6, lane = t & 63, quad = lane >> 4, l15 = lane & 15;
  int m0 = (half << 7) + (wave << 5);
  const u16* Xr = X + (((size_t)b * 64 + y) << 14);
  const u16* Xi = X + (((size_t)b * 64 + 32 + y) << 14);
  const u16* Wr = W + (((size_t)(b * 32 + y)) << 13);
  const u16* Wi = Wr + 4096;
  f32x4 z = {0.f, 0.f, 0.f, 0.f};
  f32x4 accP[2][4], accQ[2][4];
#pragma unroll
  for (int rt = 0; rt < 2; ++rt)
#pragma unroll
    for (int ct = 0; ct < 4; ++ct){ accP[rt][ct] = z; accQ[rt][ct] = z; }
  for (int k0 = 0; k0 < 64; k0 += 32){
    bf8v wr[4], wi[4], wn[4];
#pragma unroll
    for (int ct = 0; ct < 4; ++ct){
      int o = (ct << 4) + l15;
      wr[ct] = *(const bf8v*)(Wr + (o << 6) + k0 + (quad << 3));
      wi[ct] = *(const bf8v*)(Wi + (o << 6) + k0 + (quad << 3));
      wn[ct] = bneg(wi[ct]);
    }
#pragma unroll
    for (int rt = 0; rt < 2; ++rt){
      int m = m0 + (rt << 4) + l15;
      bf8v ar = *(const bf8v*)(Xr + (m << 6) + k0 + (quad << 3));
      bf8v ai = *(const bf8v*)(Xi + (m << 6) + k0 + (quad << 3));
#pragma unroll
      for (int ct = 0; ct < 4; ++ct){
        accP[rt][ct] = MFMA16(ar, wr[ct], accP[rt][ct]);
        accP[rt][ct] = MFMA16(ai, wn[ct], accP[rt][ct]);
        accQ[rt][ct] = MFMA16(ar, wi[ct], accQ[rt][ct]);
        accQ[rt][ct] = MFMA16(ai, wr[ct], accQ[rt][ct]);
      }
    }
  }
  u16* Pp = PQ + (((size_t)b * 64 + y) << 14);
  u16* Qp = PQ + (((size_t)b * 64 + 32 + y) << 14);
#pragma unroll
  for (int rt = 0; rt < 2; ++rt)
#pragma unroll
    for (int ct = 0; ct < 4; ++ct)
#pragma unroll
      for (int r = 0; r < 4; ++r){
        int m = m0 + (rt << 4) + (quad << 2) + r;
        int o = (ct << 4) + l15;
        Pp[(m << 6) + o] = f2bf(accP[rt][ct][r]);
        Qp[(m << 6) + o] = f2bf(accQ[rt][ct][r]);
      }
}

// ---------------- K5: inverse-y. per (b,m): g[b][m][n][o] = By(256x64) @ PQy[b][:][m][:]
__global__ __launch_bounds__(256)
void k_inv_y(const u16* __restrict__ PQ, const u16* __restrict__ Bas, u16* __restrict__ g){
  int blk = blockIdx.x, b = blk >> 8, m = blk & 255;
  __shared__ u16 Bld[64][72];   // [o][u]
  int t = threadIdx.x;
  {
    int u = t >> 2, o0 = (t & 3) << 4;
    const u16* p = PQ + (((size_t)b * 64 + u) << 14) + (m << 6) + o0;
    uint4 v0 = *(const uint4*)p;
    uint4 v1 = *(const uint4*)(p + 8);
    u16* d = &Bld[o0][u];
    const u16* e = (const u16*)&v0;
#pragma unroll
    for (int j = 0; j < 8; ++j) d[j * 72] = e[j];
    e = (const u16*)&v1;
#pragma unroll
    for (int j = 0; j < 8; ++j) d[(8 + j) * 72] = e[j];
  }
  __syncthreads();
  int wave = t >> 6, lane = t & 63, quad = lane >> 4, l15 = lane & 15;
  f32x4 z = {0.f, 0.f, 0.f, 0.f};
  f32x4 acc[4][4];
#pragma unroll
  for (int rt = 0; rt < 4; ++rt)
#pragma unroll
    for (int ct = 0; ct < 4; ++ct) acc[rt][ct] = z;
  for (int k0 = 0; k0 < 64; k0 += 32){
    bf8v bb[4];
#pragma unroll
    for (int ct = 0; ct < 4; ++ct)
      bb[ct] = *(const bf8v*)(&Bld[(ct << 4) + l15][k0 + (quad << 3)]);
#pragma unroll
    for (int rt = 0; rt < 4; ++rt){
      int n = (wave << 6) + (rt << 4) + l15;
      bf8v a = *(const bf8v*)(Bas + (n << 6) + k0 + (quad << 3));
#pragma unroll
      for (int ct = 0; ct < 4; ++ct) acc[rt][ct] = MFMA16(a, bb[ct], acc[rt][ct]);
    }
  }
  u16* gp = g + ((size_t)blk << 14);
#pragma unroll
  for (int rt = 0; rt < 4; ++rt)
#pragma unroll
    for (int ct = 0; ct < 4; ++ct)
#pragma unroll
      for (int r = 0; r < 4; ++r){
        int n = (wave << 6) + (rt << 4) + (quad << 2) + r;
        int o = (ct << 4) + l15;
        gp[(n << 6) + o] = f2bf(acc[rt][ct][r]);
      }
}

// ---------------- K6: inverse-x, accumulated into g. per (b,n): Bx(256x64) @ PQx[b][:][n][:]
__global__ __launch_bounds__(256)
void k_inv_x(const u16* __restrict__ PQ, const u16* __restrict__ Bas, u16* __restrict__ g){
  int blk = blockIdx.x, b = blk >> 8, nn = blk & 255;
  __shared__ u16 Bld[64][72];    // [o][u]
  __shared__ u16 ld2[256][72];   // [m][o], bf16
  int t = threadIdx.x;
  {
    int u = t >> 2, o0 = (t & 3) << 4;
    const u16* p = PQ + (((size_t)b * 64 + u) << 14) + (nn << 6) + o0;
    uint4 v0 = *(const uint4*)p;
    uint4 v1 = *(const uint4*)(p + 8);
    u16* d = &Bld[o0][u];
    const u16* e = (const u16*)&v0;
#pragma unroll
    for (int j = 0; j < 8; ++j) d[j * 72] = e[j];
    e = (const u16*)&v1;
#pragma unroll
    for (int j = 0; j < 8; ++j) d[(8 + j) * 72] = e[j];
  }
  __syncthreads();
  int wave = t >> 6, lane = t & 63, quad = lane >> 4, l15 = lane & 15;
  f32x4 z = {0.f, 0.f, 0.f, 0.f};
  f32x4 acc[4][4];
#pragma unroll
  for (int rt = 0; rt < 4; ++rt)
#pragma unroll
    for (int ct = 0; ct < 4; ++ct) acc[rt][ct] = z;
  for (int k0 = 0; k0 < 64; k0 += 32){
    bf8v bb[4];
#pragma unroll
    for (int ct = 0; ct < 4; ++ct)
      bb[ct] = *(const bf8v*)(&Bld[(ct << 4) + l15][k0 + (quad << 3)]);
#pragma unroll
    for (int rt = 0; rt < 4; ++rt){
      int mr = (wave << 6) + (rt << 4) + l15;
      bf8v a = *(const bf8v*)(Bas + (mr << 6) + k0 + (quad << 3));
#pragma unroll
      for (int ct = 0; ct < 4; ++ct) acc[rt][ct] = MFMA16(a, bb[ct], acc[rt][ct]);
    }
  }
#pragma unroll
  for (int rt = 0; rt < 4; ++rt)
#pragma unroll
    for (int ct = 0; ct < 4; ++ct)
#pragma unroll
      for (int r = 0; r < 4; ++r){
        int mr = (wave << 6) + (rt << 4) + (quad << 2) + r;
        ld2[mr][(ct << 4) + l15] = f2bf(acc[rt][ct][r]);
      }
  __syncthreads();
  {
    u16* gp = g + (((size_t)(b * 256 + t)) << 14) + (nn << 6);
    for (int c = 0; c < 8; ++c){
      uint4 v = *(const uint4*)(gp + (c << 3));
      const u16* e = (const u16*)&v;
      u32 wv[4];
#pragma unroll
      for (int jj = 0; jj < 4; ++jj){
        float a0 = bf2f(e[2 * jj])     + bf2f(ld2[t][c * 8 + 2 * jj]);
        float a1 = bf2f(e[2 * jj + 1]) + bf2f(ld2[t][c * 8 + 2 * jj + 1]);
        wv[jj] = (u32)f2bf(a0) | ((u32)f2bf(a1) << 16);
      }
      uint4 nv = {wv[0], wv[1], wv[2], wv[3]};
      *(uint4*)(gp + (c << 3)) = nv;
    }
  }
}

// ---------------- K7 v2: MLP + LayerNorm, weight-stationary.
// Old version: every wave re-streamed w1T+w2T (64KB) from global per 16-row
// tile as 16-cacheline gathers -> latency-bound (MfmaUtil 5%, VALUBusy 15%).
// Now: per block, stage w2T once in LDS (32KB, XOR-swizzled, conflict-free
// b128 reads) and keep w1 A-fragments resident in 128 VGPRs; loop NCHUNK
// 64-row tiles (16 rows/wave).
// GEMM1 is computed SWAPPED (h1^T = w1T_tile @ g^T; g's A-frag layout equals
// g^T's B-frag layout, so g loads are unchanged). Each lane then holds 4
// consecutive h1 columns: bias is one aligned float4, and the pack goes out
// as ONE ds_write_b64 per ct (16 writes vs 64 scalar b16 + f2bf emulation).
// GEMM2 reads h1 back as standard A-frags from the same swizzled layout.
// No __syncthreads in the main loop: h1 buffers are wave-private, ordered by
// lgkmcnt(0) + sched_barrier (rule: inline-asm wait needs sched_barrier(0)).
// LDS 64KB -> 2 blocks/CU; target ~240 VGPR -> 2 waves/SIMD.
#define NCHUNK 8
__global__ __launch_bounds__(256, 2)
void k_mlp(const u16* __restrict__ g, const u16* __restrict__ w1T, const float* __restrict__ b1,
           const u16* __restrict__ w2T, const float* __restrict__ b2,
           const float* __restrict__ gamma, const float* __restrict__ beta,
           float* __restrict__ out){
  __shared__ u16 w2s[64 * 256];     // [o][k ^ ((o&7)<<3)]
  __shared__ u16 h1s[4][16 * 256];  // per-wave [row][c ^ ((row&7)<<3)]
  int t = threadIdx.x;
  int wave = t >> 6, lane = t & 63, quad = lane >> 4, l15 = lane & 15;

  // ---- stage w2T -> LDS (coalesced 16B/thread, 8 rounds), swizzled
#pragma unroll
  for (int c8 = 0; c8 < 8; ++c8){
    int idx = (c8 << 8) + t;              // 2048 chunks of 8 u16
    int row = idx >> 5, col = (idx & 31) << 3;
    uint4 v = *(const uint4*)(w2T + (row << 8) + col);
    *(uint4*)(&w2s[(row << 8) + (col ^ ((row & 7) << 3))]) = v;
  }
  // ---- preload w1 A-fragments once: lane holds w1T[ct*16+l15][kk*32+quad*8+j]
  bf8v w1f[16][2];
#pragma unroll
  for (int ct = 0; ct < 16; ++ct){
    const u16* p = w1T + (((ct << 4) + l15) << 6) + (quad << 3);
    w1f[ct][0] = *(const bf8v*)(p);
    w1f[ct][1] = *(const bf8v*)(p + 32);
  }
  float b2c[4], gmc[4], btc[4];
#pragma unroll
  for (int ct = 0; ct < 4; ++ct){
    int o = (ct << 4) + l15;
    b2c[ct] = b2[o]; gmc[ct] = gamma[o]; btc[ct] = beta[o];
  }
  __syncthreads();   // w2s ready (only barrier in the kernel)

  const int sw = (l15 & 7) << 3;
  u16* hw = h1s[wave];
  size_t row0 = (((size_t)blockIdx.x * NCHUNK) << 6) + (wave << 4);
  const u16* gA = g + ((row0 + l15) << 6) + (quad << 3);
  bf8v a0 = *(const bf8v*)(gA);
  bf8v a1 = *(const bf8v*)(gA + 32);
  f32x4 z = {0.f, 0.f, 0.f, 0.f};
#pragma unroll 1
  for (int it = 0; it < NCHUNK; ++it){
    size_t rowt = row0 + ((size_t)it << 6);
    // prefetch next tile's g fragments (reg double-buffer)
    bf8v n0 = a0, n1 = a1;
    if (it + 1 < NCHUNK){
      const u16* gN = gA + ((size_t)(it + 1) << 12);   // +64 rows * 64 cols
      n0 = *(const bf8v*)(gN);
      n1 = *(const bf8v*)(gN + 32);
    }
    // ---- GEMM1 (swapped): acc1[ct][r] = h1[rowt+l15][ct*16 + quad*4 + r]
    f32x4 acc1[16];
#pragma unroll
    for (int ct = 0; ct < 16; ++ct){
      f32x4 acc = MFMA16(w1f[ct][0], a0, z);
      acc1[ct] = MFMA16(w1f[ct][1], a1, acc);
    }
    // ---- bias + relu + pack: one b64 LDS write per ct
#pragma unroll
    for (int ct = 0; ct < 16; ++ct){
      int c0 = (ct << 4) + (quad << 2);
      float4 bv = *(const float4*)(b1 + c0);
      float v0 = fmaxf(acc1[ct][0] + bv.x, 0.f);
      float v1 = fmaxf(acc1[ct][1] + bv.y, 0.f);
      float v2 = fmaxf(acc1[ct][2] + bv.z, 0.f);
      float v3 = fmaxf(acc1[ct][3] + bv.w, 0.f);
      __hip_bfloat162 p0 = __float22bfloat162_rn(make_float2(v0, v1));
      __hip_bfloat162 p1 = __float22bfloat162_rn(make_float2(v2, v3));
      uint2 wv;
      wv.x = *reinterpret_cast<u32*>(&p0);
      wv.y = *reinterpret_cast<u32*>(&p1);
      *(uint2*)(&hw[(l15 << 8) + (c0 ^ sw)]) = wv;
    }
    // wave-private LDS write->read ordering (no barrier needed)
    asm volatile("s_waitcnt lgkmcnt(0)" ::: "memory");
    __builtin_amdgcn_sched_barrier(0);
    // ---- GEMM2: d2(16x64) = h1(16x256) @ w2 (weights from LDS)
    f32x4 acc2[4] = {z, z, z, z};
#pragma unroll
    for (int k0 = 0; k0 < 256; k0 += 32){
      int koff = (k0 + (quad << 3)) ^ sw;
      bf8v a = *(const bf8v*)(&hw[(l15 << 8) + koff]);
#pragma unroll
      for (int ct = 0; ct < 4; ++ct){
        bf8v bb = *(const bf8v*)(&w2s[(((ct << 4) + l15) << 8) + koff]);
        acc2[ct] = MFMA16(a, bb, acc2[ct]);
      }
    }
    a0 = n0; a1 = n1;
    // ---- bias + LN in registers (reduce across the 16 lanes of each quad)
    float sum[4] = {0.f, 0.f, 0.f, 0.f}, ssq[4] = {0.f, 0.f, 0.f, 0.f};
#pragma unroll
    for (int ct = 0; ct < 4; ++ct)
#pragma unroll
      for (int r = 0; r < 4; ++r){
        float v = acc2[ct][r] + b2c[ct];
        sum[r] += v; ssq[r] += v * v;
      }
#pragma unroll
    for (int r = 0; r < 4; ++r){
#pragma unroll
      for (int mask = 1; mask < 16; mask <<= 1){
        sum[r] += __shfl_xor(sum[r], mask);
        ssq[r] += __shfl_xor(ssq[r], mask);
      }
    }
#pragma unroll
    for (int r = 0; r < 4; ++r){
      float mu = sum[r] * 0.015625f;
      float var = ssq[r] * 0.015625f - mu * mu;
      float rs = rsqrtf(var + 1e-5f);
      size_t rowg = rowt + (quad << 2) + r;
#pragma unroll
      for (int ct = 0; ct < 4; ++ct){
        float v = acc2[ct][r] + b2c[ct];
        out[(rowg << 6) + (ct << 4) + l15] = (v - mu) * rs * gmc[ct] + btc[ct];
      }
    }
  }
}

extern "C" void kernel_launch(void* const* d_in, const int* in_sizes, int n_in,
                              void* d_out, int out_size, void* d_ws, size_t ws_size,
                              hipStream_t stream){
  const float* x   = (const float*)d_in[0];
  const float* att = (const float*)d_in[1];
  const float* fwy = (const float*)d_in[2];
  const float* fwx = (const float*)d_in[3];
  const float* w1  = (const float*)d_in[4];
  const float* b1  = (const float*)d_in[5];
  const float* w2  = (const float*)d_in[6];
  const float* b2  = (const float*)d_in[7];
  const float* gm  = (const float*)d_in[8];
  const float* bt  = (const float*)d_in[9];
  u16* ws = (u16*)d_ws;
  u16* G   = ws + OFF_G;
  u16* Wy  = ws + OFF_WY;
  u16* Wx  = ws + OFF_WX;
  u16* Xy  = ws + OFF_XY;
  u16* Xx  = ws + OFF_XX;
  u16* PQy = ws + OFF_PQY;
  u16* PQx = ws + OFF_PQX;
  u16* Ey  = ws + OFF_EY;
  u16* Ex  = ws + OFF_EX;
  u16* By  = ws + OFF_BY;
  u16* Bx  = ws + OFF_BX;
  u16* w1T = ws + OFF_W1T;
  u16* w2T = ws + OFF_W2T;

  k_weights<<<dim3(512), dim3(256), 0, stream>>>(att, fwy, fwx, Wy, Wx);
  k_basis<<<dim3(64), dim3(256), 0, stream>>>(Ey, Ex, By, Bx, w1, w2, w1T, w2T);
  k_fwd<<<dim3(2048), dim3(256), 0, stream>>>(x, Ey, Xy, 0);
  k_mix<<<dim3(512), dim3(256), 0, stream>>>(Xy, Wy, PQy);
  k_fwd<<<dim3(2048), dim3(256), 0, stream>>>(x, Ex, Xx, 1);
  k_mix<<<dim3(512), dim3(256), 0, stream>>>(Xx, Wx, PQx);
  k_inv_y<<<dim3(2048), dim3(256), 0, stream>>>(PQy, By, G);
  k_inv_x<<<dim3(2048), dim3(256), 0, stream>>>(PQx, Bx, G);
  k_mlp<<<dim3(1024), dim3(256), 0, stream>>>(G, w1T, b1, w2T, b2, gm, bt, (float*)d_out);
}

// Round 2
// 526.435 us; speedup vs baseline: 1.2440x; 1.0084x over previous
//
#include <hip/hip_runtime.h>
#include <hip/hip_bf16.h>

typedef unsigned short u16;
typedef unsigned int u32;
typedef __attribute__((ext_vector_type(8))) __bf16 bf8v;   // MFMA A/B operand
typedef __attribute__((ext_vector_type(4))) float f32x4;   // MFMA C/D

#define MFMA16(a, b, c) __builtin_amdgcn_mfma_f32_16x16x32_bf16((a), (b), (c), 0, 0, 0)

__device__ __forceinline__ float bf2f(u16 h){
  union { u32 u; float f; } v; v.u = ((u32)h) << 16; return v.f;
}
__device__ __forceinline__ u16 f2bf(float f){
  union { float f; u32 u; } v; v.f = f;
  u32 u = v.u;
  return (u16)((u + 0x7FFFu + ((u >> 16) & 1u)) >> 16);
}
__device__ __forceinline__ bf8v bneg(bf8v v){
  union { bf8v b; u16 u[8]; } a; a.b = v;
#pragma unroll
  for (int j = 0; j < 8; ++j) a.u[j] ^= 0x8000u;
  return a.b;
}

// ---- workspace layout (u16 element offsets); bf16 intermediates ----
static const size_t OFF_G   = 0;
static const size_t OFF_WY  = 33554432;
static const size_t OFF_WX  = 37748736;
static const size_t OFF_XY  = 41943040;
static const size_t OFF_XX  = 50331648;
static const size_t OFF_PQY = 58720256;
static const size_t OFF_PQX = 67108864;
static const size_t OFF_EY  = 75497472;
static const size_t OFF_EX  = OFF_EY + 16384;
static const size_t OFF_BY  = OFF_EX + 16384;
static const size_t OFF_BX  = OFF_BY + 16384;
static const size_t OFF_W1T = OFF_BX + 16384;
static const size_t OFF_W2T = OFF_W1T + 16384;

// ---------------- K0: mixing weights  W[b][y][c][o][i] = sum_k att[b][k]*fw[k][i][o][y][c]
__global__ __launch_bounds__(256)
void k_weights(const float* __restrict__ att, const float* __restrict__ fwy,
               const float* __restrict__ fwx, u16* __restrict__ Wy, u16* __restrict__ Wx){
  int blk = blockIdx.x;                 // 512 blocks: branch*256 + b*32 + y
  int branch = blk >> 8; int rem = blk & 255; int b = rem >> 5, y = rem & 31;
  const float* fw = branch ? fwx : fwy;
  u16* W = branch ? Wx : Wy;
  float ak[4];
#pragma unroll
  for (int k = 0; k < 4; ++k) ak[k] = att[b * 4 + k];
  __shared__ u16 Wt[2][64][72];
  int t = threadIdx.x;
  int o = t >> 2, i0 = (t & 3) << 4;
  for (int j = 0; j < 16; ++j){
    int i = i0 + j;
    float s0 = 0.f, s1 = 0.f;
#pragma unroll
    for (int k = 0; k < 4; ++k){
      float2 v = *(const float2*)(fw + ((((size_t)((k * 64 + i) * 64 + o)) * 32 + y) << 1));
      s0 += ak[k] * v.x;
      s1 += ak[k] * v.y;
    }
    Wt[0][o][i] = f2bf(s0);
    Wt[1][o][i] = f2bf(s1);
  }
  __syncthreads();
  {
    int c = t >> 7, oo = (t >> 1) & 63, ih = (t & 1) << 5;
    u16* dst = W + ((((size_t)(b * 32 + y)) * 2 + c) << 12) + (oo << 6) + ih;
    const u16* src = &Wt[c][oo][ih];
    uint4 v0 = *(const uint4*)(src);
    uint4 v1 = *(const uint4*)(src + 8);
    uint4 v2 = *(const uint4*)(src + 16);
    uint4 v3 = *(const uint4*)(src + 24);
    *(uint4*)(dst) = v0; *(uint4*)(dst + 8) = v1;
    *(uint4*)(dst + 16) = v2; *(uint4*)(dst + 24) = v3;
  }
}

// ---------------- K0b: basis matrices + weight transposes (fp32 -> bf16)
__global__ __launch_bounds__(256)
void k_basis(u16* __restrict__ Ey, u16* __restrict__ Ex,
             u16* __restrict__ By, u16* __restrict__ Bx,
             const float* __restrict__ w1, const float* __restrict__ w2,
             u16* __restrict__ w1T, u16* __restrict__ w2T){
  int idx = blockIdx.x * 256 + threadIdx.x;   // grid 64 -> idx < 16384
  const float C256 = 0.0245436926066f;  // 2*pi/256
  const float C510 = 0.0123199711905f;  // 2*pi/510
  {
    int u = idx >> 8, n = idx & 255;
    int y = u & 31;
    float ang = C256 * (float)((n * y) & 255);
    float v = (u < 32) ? cosf(ang) : -sinf(ang);
    Ey[idx] = f2bf(v);
    float vx;
    if (u < 32) vx = (n == 0) ? 1.f : (n == 255 ? ((u & 1) ? -1.f : 1.f) : 0.f);
    else        vx = -2.f * sinf(C510 * (float)((n * y) % 510));
    Ex[idx] = f2bf(vx);
  }
  {
    int n = idx >> 6, u = idx & 63;
    int y = u & 31;
    float ang = C256 * (float)((n * y) & 255);
    float v;
    if (u == 0)       v = 0.00390625f;                // 1/256
    else if (u < 32)  v = 0.0078125f * cosf(ang);     // 2/256 cos
    else if (u == 32) v = 0.f;                        // Im(F0) dropped by irfft
    else              v = -0.0078125f * sinf(ang);
    By[idx] = f2bf(v);
    float angx = C510 * (float)((n * y) % 510);
    float vx;
    if (u == 0)       vx = 1.f / 510.f;
    else if (u < 32)  vx = (2.f / 510.f) * cosf(angx);
    else if (u == 32) vx = 0.f;
    else              vx = -(2.f / 510.f) * sinf(angx);
    Bx[idx] = f2bf(vx);
  }
  {
    int k = idx >> 8, c = idx & 255;      // w1 (64,256)
    w1T[c * 64 + k] = f2bf(w1[idx]);
    int k2 = idx >> 6, o = idx & 63;      // w2 (256,64)
    w2T[o * 256 + k2] = f2bf(w2[idx]);
  }
}

// ---------------- K1/K3: forward transform.  D(64u x 64i) = E(64x256) @ xslice(256x64)
#define SWZ(i) ((((i) >> 3) & 7) << 3)
__global__ __launch_bounds__(256)
void k_fwd(const float* __restrict__ xin, const u16* __restrict__ E,
           u16* __restrict__ Xout, int mode){
  int blk = blockIdx.x; int b = blk >> 8, s = blk & 255;
  const float* xbase; size_t rstride;
  if (mode == 0){ xbase = xin + ((size_t)blk << 14); rstride = 64; }       // rows = n
  else          { xbase = xin + ((size_t)b << 22) + ((size_t)s << 6); rstride = 16384; } // rows = m
  __shared__ u16 xs[64][264];   // [i][row^swizzle]
  int t = threadIdx.x;
  {
    int r0 = t >> 4, i0 = (t & 15) << 2;
    int sw = SWZ(i0);
    for (int it = 0; it < 16; ++it){
      int r = r0 + (it << 4);
      float4 v = *(const float4*)(xbase + (size_t)r * rstride + i0);
      int rs = r ^ sw;
      xs[i0 + 0][rs] = f2bf(v.x);
      xs[i0 + 1][rs] = f2bf(v.y);
      xs[i0 + 2][rs] = f2bf(v.z);
      xs[i0 + 3][rs] = f2bf(v.w);
    }
  }
  __syncthreads();
  int wave = t >> 6, lane = t & 63, quad = lane >> 4, l15 = lane & 15;
  int urow = (wave << 4) + l15;
  f32x4 z = {0.f, 0.f, 0.f, 0.f};
  f32x4 acc[4] = {z, z, z, z};
  for (int k0 = 0; k0 < 256; k0 += 32){
    bf8v a = *(const bf8v*)(E + (urow << 8) + k0 + (quad << 3));
#pragma unroll
    for (int ct = 0; ct < 4; ++ct){
      int i = (ct << 4) + l15;
      bf8v bb = *(const bf8v*)(&xs[i][(k0 + (quad << 3)) ^ SWZ(i)]);
      acc[ct] = MFMA16(a, bb, acc[ct]);
    }
  }
#pragma unroll
  for (int ct = 0; ct < 4; ++ct)
#pragma unroll
    for (int r = 0; r < 4; ++r){
      int u = (wave << 4) + (quad << 2) + r;
      int col = (ct << 4) + l15;
      Xout[(((size_t)b * 64 + u) << 14) + (s << 6) + col] = f2bf(acc[ct][r]);
    }
}

// ---------------- K2/K4: mode mixing. per (b,y,half): P=Xr@Wr-Xi@Wi, Q=Xr@Wi+Xi@Wr
__global__ __launch_bounds__(256)
void k_mix(const u16* __restrict__ X, const u16* __restrict__ W, u16* __restrict__ PQ){
  int blk = blockIdx.x;           // 512: ((b*32+y)*2 + half)
  int half = blk & 1, by = blk >> 1, b = by >> 5, y = by & 31;
  int t = threadIdx.x, wave = t >> 6, lane = t & 63, quad = lane >> 4, l15 = lane & 15;
  int m0 = (half << 7) + (wave << 5);
  const u16* Xr = X + (((size_t)b * 64 + y) << 14);
  const u16* Xi = X + (((size_t)b * 64 + 32 + y) << 14);
  const u16* Wr = W + (((size_t)(b * 32 + y)) << 13);
  const u16* Wi = Wr + 4096;
  f32x4 z = {0.f, 0.f, 0.f, 0.f};
  f32x4 accP[2][4], accQ[2][4];
#pragma unroll
  for (int rt = 0; rt < 2; ++rt)
#pragma unroll
    for (int ct = 0; ct < 4; ++ct){ accP[rt][ct] = z; accQ[rt][ct] = z; }
  for (int k0 = 0; k0 < 64; k0 += 32){
    bf8v wr[4], wi[4], wn[4];
#pragma unroll
    for (int ct = 0; ct < 4; ++ct){
      int o = (ct << 4) + l15;
      wr[ct] = *(const bf8v*)(Wr + (o << 6) + k0 + (quad << 3));
      wi[ct] = *(const bf8v*)(Wi + (o << 6) + k0 + (quad << 3));
      wn[ct] = bneg(wi[ct]);
    }
#pragma unroll
    for (int rt = 0; rt < 2; ++rt){
      int m = m0 + (rt << 4) + l15;
      bf8v ar = *(const bf8v*)(Xr + (m << 6) + k0 + (quad << 3));
      bf8v ai = *(const bf8v*)(Xi + (m << 6) + k0 + (quad << 3));
#pragma unroll
      for (int ct = 0; ct < 4; ++ct){
        accP[rt][ct] = MFMA16(ar, wr[ct], accP[rt][ct]);
        accP[rt][ct] = MFMA16(ai, wn[ct], accP[rt][ct]);
        accQ[rt][ct] = MFMA16(ar, wi[ct], accQ[rt][ct]);
        accQ[rt][ct] = MFMA16(ai, wr[ct], accQ[rt][ct]);
      }
    }
  }
  u16* Pp = PQ + (((size_t)b * 64 + y) << 14);
  u16* Qp = PQ + (((size_t)b * 64 + 32 + y) << 14);
#pragma unroll
  for (int rt = 0; rt < 2; ++rt)
#pragma unroll
    for (int ct = 0; ct < 4; ++ct)
#pragma unroll
      for (int r = 0; r < 4; ++r){
        int m = m0 + (rt << 4) + (quad << 2) + r;
        int o = (ct << 4) + l15;
        Pp[(m << 6) + o] = f2bf(accP[rt][ct][r]);
        Qp[(m << 6) + o] = f2bf(accQ[rt][ct][r]);
      }
}

// ---------------- K5: inverse-y. per (b,m): g[b][m][n][o] = By(256x64) @ PQy[b][:][m][:]
__global__ __launch_bounds__(256)
void k_inv_y(const u16* __restrict__ PQ, const u16* __restrict__ Bas, u16* __restrict__ g){
  int blk = blockIdx.x, b = blk >> 8, m = blk & 255;
  __shared__ u16 Bld[64][72];   // [o][u]
  int t = threadIdx.x;
  {
    int u = t >> 2, o0 = (t & 3) << 4;
    const u16* p = PQ + (((size_t)b * 64 + u) << 14) + (m << 6) + o0;
    uint4 v0 = *(const uint4*)p;
    uint4 v1 = *(const uint4*)(p + 8);
    u16* d = &Bld[o0][u];
    const u16* e = (const u16*)&v0;
#pragma unroll
    for (int j = 0; j < 8; ++j) d[j * 72] = e[j];
    e = (const u16*)&v1;
#pragma unroll
    for (int j = 0; j < 8; ++j) d[(8 + j) * 72] = e[j];
  }
  __syncthreads();
  int wave = t >> 6, lane = t & 63, quad = lane >> 4, l15 = lane & 15;
  f32x4 z = {0.f, 0.f, 0.f, 0.f};
  f32x4 acc[4][4];
#pragma unroll
  for (int rt = 0; rt < 4; ++rt)
#pragma unroll
    for (int ct = 0; ct < 4; ++ct) acc[rt][ct] = z;
  for (int k0 = 0; k0 < 64; k0 += 32){
    bf8v bb[4];
#pragma unroll
    for (int ct = 0; ct < 4; ++ct)
      bb[ct] = *(const bf8v*)(&Bld[(ct << 4) + l15][k0 + (quad << 3)]);
#pragma unroll
    for (int rt = 0; rt < 4; ++rt){
      int n = (wave << 6) + (rt << 4) + l15;
      bf8v a = *(const bf8v*)(Bas + (n << 6) + k0 + (quad << 3));
#pragma unroll
      for (int ct = 0; ct < 4; ++ct) acc[rt][ct] = MFMA16(a, bb[ct], acc[rt][ct]);
    }
  }
  u16* gp = g + ((size_t)blk << 14);
#pragma unroll
  for (int rt = 0; rt < 4; ++rt)
#pragma unroll
    for (int ct = 0; ct < 4; ++ct)
#pragma unroll
      for (int r = 0; r < 4; ++r){
        int n = (wave << 6) + (rt << 4) + (quad << 2) + r;
        int o = (ct << 4) + l15;
        gp[(n << 6) + o] = f2bf(acc[rt][ct][r]);
      }
}

// ---------------- K6: inverse-x, accumulated into g. per (b,n): Bx(256x64) @ PQx[b][:][n][:]
__global__ __launch_bounds__(256)
void k_inv_x(const u16* __restrict__ PQ, const u16* __restrict__ Bas, u16* __restrict__ g){
  int blk = blockIdx.x, b = blk >> 8, nn = blk & 255;
  __shared__ u16 Bld[64][72];    // [o][u]
  __shared__ u16 ld2[256][72];   // [m][o], bf16
  int t = threadIdx.x;
  {
    int u = t >> 2, o0 = (t & 3) << 4;
    const u16* p = PQ + (((size_t)b * 64 + u) << 14) + (nn << 6) + o0;
    uint4 v0 = *(const uint4*)p;
    uint4 v1 = *(const uint4*)(p + 8);
    u16* d = &Bld[o0][u];
    const u16* e = (const u16*)&v0;
#pragma unroll
    for (int j = 0; j < 8; ++j) d[j * 72] = e[j];
    e = (const u16*)&v1;
#pragma unroll
    for (int j = 0; j < 8; ++j) d[(8 + j) * 72] = e[j];
  }
  __syncthreads();
  int wave = t >> 6, lane = t & 63, quad = lane >> 4, l15 = lane & 15;
  f32x4 z = {0.f, 0.f, 0.f, 0.f};
  f32x4 acc[4][4];
#pragma unroll
  for (int rt = 0; rt < 4; ++rt)
#pragma unroll
    for (int ct = 0; ct < 4; ++ct) acc[rt][ct] = z;
  for (int k0 = 0; k0 < 64; k0 += 32){
    bf8v bb[4];
#pragma unroll
    for (int ct = 0; ct < 4; ++ct)
      bb[ct] = *(const bf8v*)(&Bld[(ct << 4) + l15][k0 + (quad << 3)]);
#pragma unroll
    for (int rt = 0; rt < 4; ++rt){
      int mr = (wave << 6) + (rt << 4) + l15;
      bf8v a = *(const bf8v*)(Bas + (mr << 6) + k0 + (quad << 3));
#pragma unroll
      for (int ct = 0; ct < 4; ++ct) acc[rt][ct] = MFMA16(a, bb[ct], acc[rt][ct]);
    }
  }
#pragma unroll
  for (int rt = 0; rt < 4; ++rt)
#pragma unroll
    for (int ct = 0; ct < 4; ++ct)
#pragma unroll
      for (int r = 0; r < 4; ++r){
        int mr = (wave << 6) + (rt << 4) + (quad << 2) + r;
        ld2[mr][(ct << 4) + l15] = f2bf(acc[rt][ct][r]);
      }
  __syncthreads();
  {
    u16* gp = g + (((size_t)(b * 256 + t)) << 14) + (nn << 6);
    for (int c = 0; c < 8; ++c){
      uint4 v = *(const uint4*)(gp + (c << 3));
      const u16* e = (const u16*)&v;
      u32 wv[4];
#pragma unroll
      for (int jj = 0; jj < 4; ++jj){
        float a0 = bf2f(e[2 * jj])     + bf2f(ld2[t][c * 8 + 2 * jj]);
        float a1 = bf2f(e[2 * jj + 1]) + bf2f(ld2[t][c * 8 + 2 * jj + 1]);
        wv[jj] = (u32)f2bf(a0) | ((u32)f2bf(a1) << 16);
      }
      uint4 nv = {wv[0], wv[1], wv[2], wv[3]};
      *(uint4*)(gp + (c << 3)) = nv;
    }
  }
}

// ---------------- K7 v3: MLP + LayerNorm, column-split, register weights.
// v2 was latency-bound at 8 waves/CU: 64KB LDS (w2s + per-wave h1s) capped
// occupancy at 2 blocks/CU, and GEMM2 re-read w2s from LDS (32 b128/wave-iter).
// v3: block-iter = 64 rows shared by 4 waves.
//   GEMM1 col-split: wave w computes h1[64 rows][64w..64w+63] (swapped MFMA,
//     w1 frags = 8 bf8v in regs), packs relu to shared h1s (XOR-swizzled).
//   GEMM2 col-split: wave w computes all 64 rows x out-cols [16w,16w+16)
//     (w2 frags = 8 bf8v in regs, only h1 a-frags from LDS: 32 b128/iter).
//   LN: per-wave partial (sum,ssq) over its 16 cols via 16-lane shfl tree,
//     exchanged through 2KB LDS, finished after barrier #2.
// LDS = 32KB h1 + 2KB lnb -> 34.8KB; VGPR target <=170 (launch_bounds 256,3)
// -> 12 waves/CU (vs 8). Non-temporal out stores keep weights L2-resident.
#define NIT 4
__global__ __launch_bounds__(256, 3)
void k_mlp(const u16* __restrict__ g, const u16* __restrict__ w1T, const float* __restrict__ b1,
           const u16* __restrict__ w2T, const float* __restrict__ b2,
           const float* __restrict__ gamma, const float* __restrict__ beta,
           float* __restrict__ out){
  __shared__ u16 h1s[64 * 256];      // [row][col ^ ((row&7)<<3)]  32KB
  __shared__ float lnb[2][64][4];    // [sum/ssq][row][wave]       2KB
  int t = threadIdx.x;
  int wave = t >> 6, lane = t & 63, quad = lane >> 4, l15 = lane & 15;
  const int sw = (l15 & 7) << 3;

  // hoisted weight fragments (A-frags of w1 for this wave's 64 h1-cols)
  bf8v w1f[4][2];
#pragma unroll
  for (int ct = 0; ct < 4; ++ct){
    const u16* p = w1T + (((wave << 6) + (ct << 4) + l15) << 6) + (quad << 3);
    w1f[ct][0] = *(const bf8v*)(p);
    w1f[ct][1] = *(const bf8v*)(p + 32);
  }
  // B-frags of w2 for this wave's 16 out-cols (full K=256)
  bf8v w2f[8];
#pragma unroll
  for (int k0 = 0; k0 < 8; ++k0)
    w2f[k0] = *(const bf8v*)(w2T + (((wave << 4) + l15) << 8) + (k0 << 5) + (quad << 3));
  float4 b1c[4];
#pragma unroll
  for (int ct = 0; ct < 4; ++ct)
    b1c[ct] = *(const float4*)(b1 + (wave << 6) + (ct << 4) + (quad << 2));
  int oc = (wave << 4) + l15;
  float b2c = b2[oc], gmc = gamma[oc], btc = beta[oc];
  f32x4 z = {0.f, 0.f, 0.f, 0.f};

  size_t row0 = ((size_t)blockIdx.x * NIT) << 6;
#pragma unroll 1
  for (int it = 0; it < NIT; ++it, row0 += 64){
    // ---- phase 1: GEMM1 (swapped), cols [64w,64w+64) of all 64 rows
#pragma unroll
    for (int tr = 0; tr < 4; ++tr){
      const u16* gA = g + ((row0 + (tr << 4) + l15) << 6) + (quad << 3);
      bf8v a0 = *(const bf8v*)(gA);
      bf8v a1 = *(const bf8v*)(gA + 32);
      int row = (tr << 4) + l15;           // row&7 == l15&7 -> swizzle == sw
#pragma unroll
      for (int ct = 0; ct < 4; ++ct){
        f32x4 acc = MFMA16(w1f[ct][0], a0, z);
        acc = MFMA16(w1f[ct][1], a1, acc);
        int c0 = (wave << 6) + (ct << 4) + (quad << 2);
        float4 bv = b1c[ct];
        float v0 = fmaxf(acc[0] + bv.x, 0.f);
        float v1 = fmaxf(acc[1] + bv.y, 0.f);
        float v2 = fmaxf(acc[2] + bv.z, 0.f);
        float v3 = fmaxf(acc[3] + bv.w, 0.f);
        __hip_bfloat162 p0 = __float22bfloat162_rn(make_float2(v0, v1));
        __hip_bfloat162 p1 = __float22bfloat162_rn(make_float2(v2, v3));
        uint2 wv;
        wv.x = *reinterpret_cast<u32*>(&p0);
        wv.y = *reinterpret_cast<u32*>(&p1);
        *(uint2*)(&h1s[(row << 8) + (c0 ^ sw)]) = wv;
      }
    }
    __syncthreads();   // h1 complete

    // ---- phase 2: GEMM2, all 64 rows x out-cols [16w,16w+16), w2 from regs
    f32x4 acc2[4] = {z, z, z, z};
#pragma unroll
    for (int k0 = 0; k0 < 8; ++k0){
      int koff = (k0 << 5) + (quad << 3);
#pragma unroll
      for (int tr = 0; tr < 4; ++tr){
        bf8v a = *(const bf8v*)(&h1s[(((tr << 4) + l15) << 8) + (koff ^ sw)]);
        acc2[tr] = MFMA16(a, w2f[k0], acc2[tr]);
      }
    }
    // LN partials over this wave's 16 cols (reduce across l15 lanes)
#pragma unroll
    for (int tr = 0; tr < 4; ++tr){
#pragma unroll
      for (int r = 0; r < 4; ++r){
        float v = acc2[tr][r] + b2c;
        float s = v, q = v * v;
#pragma unroll
        for (int mask = 1; mask < 16; mask <<= 1){
          s += __shfl_xor(s, mask);
          q += __shfl_xor(q, mask);
        }
        if (l15 == 0){
          int row = (tr << 4) + (quad << 2) + r;
          lnb[0][row][wave] = s;
          lnb[1][row][wave] = q;
        }
      }
    }
    __syncthreads();   // partials complete (also guards h1 reuse next iter)

    // ---- phase 3: finish LN + non-temporal store
#pragma unroll
    for (int tr = 0; tr < 4; ++tr){
#pragma unroll
      for (int r = 0; r < 4; ++r){
        int row = (tr << 4) + (quad << 2) + r;
        float4 s4 = *(const float4*)(&lnb[0][row][0]);
        float4 q4 = *(const float4*)(&lnb[1][row][0]);
        float sum = (s4.x + s4.y) + (s4.z + s4.w);
        float ssq = (q4.x + q4.y) + (q4.z + q4.w);
        float mu = sum * 0.015625f;
        float var = ssq * 0.015625f - mu * mu;
        float rs = rsqrtf(var + 1e-5f);
        float v = acc2[tr][r] + b2c;
        __builtin_nontemporal_store((v - mu) * rs * gmc + btc,
                                    out + ((row0 + row) << 6) + oc);
      }
    }
  }
}

extern "C" void kernel_launch(void* const* d_in, const int* in_sizes, int n_in,
                              void* d_out, int out_size, void* d_ws, size_t ws_size,
                              hipStream_t stream){
  const float* x   = (const float*)d_in[0];
  const float* att = (const float*)d_in[1];
  const float* fwy = (const float*)d_in[2];
  const float* fwx = (const float*)d_in[3];
  const float* w1  = (const float*)d_in[4];
  const float* b1  = (const float*)d_in[5];
  const float* w2  = (const float*)d_in[6];
  const float* b2  = (const float*)d_in[7];
  const float* gm  = (const float*)d_in[8];
  const float* bt  = (const float*)d_in[9];
  u16* ws = (u16*)d_ws;
  u16* G   = ws + OFF_G;
  u16* Wy  = ws + OFF_WY;
  u16* Wx  = ws + OFF_WX;
  u16* Xy  = ws + OFF_XY;
  u16* Xx  = ws + OFF_XX;
  u16* PQy = ws + OFF_PQY;
  u16* PQx = ws + OFF_PQX;
  u16* Ey  = ws + OFF_EY;
  u16* Ex  = ws + OFF_EX;
  u16* By  = ws + OFF_BY;
  u16* Bx  = ws + OFF_BX;
  u16* w1T = ws + OFF_W1T;
  u16* w2T = ws + OFF_W2T;

  k_weights<<<dim3(512), dim3(256), 0, stream>>>(att, fwy, fwx, Wy, Wx);
  k_basis<<<dim3(64), dim3(256), 0, stream>>>(Ey, Ex, By, Bx, w1, w2, w1T, w2T);
  k_fwd<<<dim3(2048), dim3(256), 0, stream>>>(x, Ey, Xy, 0);
  k_mix<<<dim3(512), dim3(256), 0, stream>>>(Xy, Wy, PQy);
  k_fwd<<<dim3(2048), dim3(256), 0, stream>>>(x, Ex, Xx, 1);
  k_mix<<<dim3(512), dim3(256), 0, stream>>>(Xx, Wx, PQx);
  k_inv_y<<<dim3(2048), dim3(256), 0, stream>>>(PQy, By, G);
  k_inv_x<<<dim3(2048), dim3(256), 0, stream>>>(PQx, Bx, G);
  k_mlp<<<dim3(2048), dim3(256), 0, stream>>>(G, w1T, b1, w2T, b2, gm, bt, (float*)d_out);
}

// Round 3
// 507.685 us; speedup vs baseline: 1.2900x; 1.0369x over previous
//
#include <hip/hip_runtime.h>
#include <hip/hip_bf16.h>

typedef unsigned short u16;
typedef unsigned int u32;
typedef __attribute__((ext_vector_type(8))) __bf16 bf8v;   // MFMA A/B operand
typedef __attribute__((ext_vector_type(4))) float f32x4;   // MFMA C/D

#define MFMA16(a, b, c) __builtin_amdgcn_mfma_f32_16x16x32_bf16((a), (b), (c), 0, 0, 0)

__device__ __forceinline__ float bf2f(u16 h){
  union { u32 u; float f; } v; v.u = ((u32)h) << 16; return v.f;
}
__device__ __forceinline__ u16 f2bf(float f){
  union { float f; u32 u; } v; v.f = f;
  u32 u = v.u;
  return (u16)((u + 0x7FFFu + ((u >> 16) & 1u)) >> 16);
}
__device__ __forceinline__ bf8v bneg(bf8v v){
  union { bf8v b; u16 u[8]; } a; a.b = v;
#pragma unroll
  for (int j = 0; j < 8; ++j) a.u[j] ^= 0x8000u;
  return a.b;
}

// ---- workspace layout (u16 element offsets); bf16 intermediates ----
static const size_t OFF_G   = 0;
static const size_t OFF_WY  = 33554432;
static const size_t OFF_WX  = 37748736;
static const size_t OFF_XY  = 41943040;
static const size_t OFF_XX  = 50331648;
static const size_t OFF_PQY = 58720256;
static const size_t OFF_PQX = 67108864;
static const size_t OFF_EY  = 75497472;
static const size_t OFF_EX  = OFF_EY + 16384;
static const size_t OFF_BY  = OFF_EX + 16384;
static const size_t OFF_BX  = OFF_BY + 16384;
static const size_t OFF_W1T = OFF_BX + 16384;
static const size_t OFF_W2T = OFF_W1T + 16384;

// ---------------- K0: mixing weights  W[b][y][c][o][i] = sum_k att[b][k]*fw[k][i][o][y][c]
__global__ __launch_bounds__(256)
void k_weights(const float* __restrict__ att, const float* __restrict__ fwy,
               const float* __restrict__ fwx, u16* __restrict__ Wy, u16* __restrict__ Wx){
  int blk = blockIdx.x;                 // 512 blocks: branch*256 + b*32 + y
  int branch = blk >> 8; int rem = blk & 255; int b = rem >> 5, y = rem & 31;
  const float* fw = branch ? fwx : fwy;
  u16* W = branch ? Wx : Wy;
  float ak[4];
#pragma unroll
  for (int k = 0; k < 4; ++k) ak[k] = att[b * 4 + k];
  __shared__ u16 Wt[2][64][72];
  int t = threadIdx.x;
  int o = t >> 2, i0 = (t & 3) << 4;
  for (int j = 0; j < 16; ++j){
    int i = i0 + j;
    float s0 = 0.f, s1 = 0.f;
#pragma unroll
    for (int k = 0; k < 4; ++k){
      float2 v = *(const float2*)(fw + ((((size_t)((k * 64 + i) * 64 + o)) * 32 + y) << 1));
      s0 += ak[k] * v.x;
      s1 += ak[k] * v.y;
    }
    Wt[0][o][i] = f2bf(s0);
    Wt[1][o][i] = f2bf(s1);
  }
  __syncthreads();
  {
    int c = t >> 7, oo = (t >> 1) & 63, ih = (t & 1) << 5;
    u16* dst = W + ((((size_t)(b * 32 + y)) * 2 + c) << 12) + (oo << 6) + ih;
    const u16* src = &Wt[c][oo][ih];
    uint4 v0 = *(const uint4*)(src);
    uint4 v1 = *(const uint4*)(src + 8);
    uint4 v2 = *(const uint4*)(src + 16);
    uint4 v3 = *(const uint4*)(src + 24);
    *(uint4*)(dst) = v0; *(uint4*)(dst + 8) = v1;
    *(uint4*)(dst + 16) = v2; *(uint4*)(dst + 24) = v3;
  }
}

// ---------------- K0b: basis matrices + weight transposes (fp32 -> bf16)
__global__ __launch_bounds__(256)
void k_basis(u16* __restrict__ Ey, u16* __restrict__ Ex,
             u16* __restrict__ By, u16* __restrict__ Bx,
             const float* __restrict__ w1, const float* __restrict__ w2,
             u16* __restrict__ w1T, u16* __restrict__ w2T){
  int idx = blockIdx.x * 256 + threadIdx.x;   // grid 64 -> idx < 16384
  const float C256 = 0.0245436926066f;  // 2*pi/256
  const float C510 = 0.0123199711905f;  // 2*pi/510
  {
    int u = idx >> 8, n = idx & 255;
    int y = u & 31;
    float ang = C256 * (float)((n * y) & 255);
    float v = (u < 32) ? cosf(ang) : -sinf(ang);
    Ey[idx] = f2bf(v);
    float vx;
    if (u < 32) vx = (n == 0) ? 1.f : (n == 255 ? ((u & 1) ? -1.f : 1.f) : 0.f);
    else        vx = -2.f * sinf(C510 * (float)((n * y) % 510));
    Ex[idx] = f2bf(vx);
  }
  {
    int n = idx >> 6, u = idx & 63;
    int y = u & 31;
    float ang = C256 * (float)((n * y) & 255);
    float v;
    if (u == 0)       v = 0.00390625f;                // 1/256
    else if (u < 32)  v = 0.0078125f * cosf(ang);     // 2/256 cos
    else if (u == 32) v = 0.f;                        // Im(F0) dropped by irfft
    else              v = -0.0078125f * sinf(ang);
    By[idx] = f2bf(v);
    float angx = C510 * (float)((n * y) % 510);
    float vx;
    if (u == 0)       vx = 1.f / 510.f;
    else if (u < 32)  vx = (2.f / 510.f) * cosf(angx);
    else if (u == 32) vx = 0.f;
    else              vx = -(2.f / 510.f) * sinf(angx);
    Bx[idx] = f2bf(vx);
  }
  {
    int k = idx >> 8, c = idx & 255;      // w1 (64,256)
    w1T[c * 64 + k] = f2bf(w1[idx]);
    int k2 = idx >> 6, o = idx & 63;      // w2 (256,64)
    w2T[o * 256 + k2] = f2bf(w2[idx]);
  }
}

// ---------------- K1 (fused): forward transforms, both modes in ONE launch.
// blk = b*512 + mode*256 + s, b-major: the ~1024 blocks in flight cover both
// modes of the same batch b concurrently, so x[b] (67MB < 256MB L3) is
// fetched from HBM once and the second access pattern hits L3.
// (v3 ran two separate launches -> 2 x 536MB HBM reads of x, ~170us.)
#define SWZ(i) ((((i) >> 3) & 7) << 3)
__global__ __launch_bounds__(256)
void k_fwd(const float* __restrict__ xin, const u16* __restrict__ Ey,
           const u16* __restrict__ Ex, u16* __restrict__ Xy, u16* __restrict__ Xx){
  int blk = blockIdx.x;                       // 4096
  int b = blk >> 9, rem = blk & 511, mode = rem >> 8, s = rem & 255;
  const u16* E = mode ? Ex : Ey;
  u16* Xout = mode ? Xx : Xy;
  const float* xbase; size_t rstride;
  if (mode == 0){ xbase = xin + (((size_t)(b << 8) + s) << 14); rstride = 64; }      // rows = n
  else          { xbase = xin + ((size_t)b << 22) + ((size_t)s << 6); rstride = 16384; } // rows = m
  __shared__ u16 xs[64][264];   // [i][row^swizzle]
  int t = threadIdx.x;
  {
    int r0 = t >> 4, i0 = (t & 15) << 2;
    int sw = SWZ(i0);
    for (int it = 0; it < 16; ++it){
      int r = r0 + (it << 4);
      float4 v = *(const float4*)(xbase + (size_t)r * rstride + i0);
      int rs = r ^ sw;
      xs[i0 + 0][rs] = f2bf(v.x);
      xs[i0 + 1][rs] = f2bf(v.y);
      xs[i0 + 2][rs] = f2bf(v.z);
      xs[i0 + 3][rs] = f2bf(v.w);
    }
  }
  __syncthreads();
  int wave = t >> 6, lane = t & 63, quad = lane >> 4, l15 = lane & 15;
  int urow = (wave << 4) + l15;
  f32x4 z = {0.f, 0.f, 0.f, 0.f};
  f32x4 acc[4] = {z, z, z, z};
  for (int k0 = 0; k0 < 256; k0 += 32){
    bf8v a = *(const bf8v*)(E + (urow << 8) + k0 + (quad << 3));
#pragma unroll
    for (int ct = 0; ct < 4; ++ct){
      int i = (ct << 4) + l15;
      bf8v bb = *(const bf8v*)(&xs[i][(k0 + (quad << 3)) ^ SWZ(i)]);
      acc[ct] = MFMA16(a, bb, acc[ct]);
    }
  }
#pragma unroll
  for (int ct = 0; ct < 4; ++ct)
#pragma unroll
    for (int r = 0; r < 4; ++r){
      int u = (wave << 4) + (quad << 2) + r;
      int col = (ct << 4) + l15;
      Xout[(((size_t)b * 64 + u) << 14) + (s << 6) + col] = f2bf(acc[ct][r]);
    }
}

// ---------------- K2/K4: mode mixing. per (b,y,half): P=Xr@Wr-Xi@Wi, Q=Xr@Wi+Xi@Wr
__global__ __launch_bounds__(256)
void k_mix(const u16* __restrict__ X, const u16* __restrict__ W, u16* __restrict__ PQ){
  int blk = blockIdx.x;           // 512: ((b*32+y)*2 + half)
  int half = blk & 1, by = blk >> 1, b = by >> 5, y = by & 31;
  int t = threadIdx.x, wave = t >> 6, lane = t & 63, quad = lane >> 4, l15 = lane & 15;
  int m0 = (half << 7) + (wave << 5);
  const u16* Xr = X + (((size_t)b * 64 + y) << 14);
  const u16* Xi = X + (((size_t)b * 64 + 32 + y) << 14);
  const u16* Wr = W + (((size_t)(b * 32 + y)) << 13);
  const u16* Wi = Wr + 4096;
  f32x4 z = {0.f, 0.f, 0.f, 0.f};
  f32x4 accP[2][4], accQ[2][4];
#pragma unroll
  for (int rt = 0; rt < 2; ++rt)
#pragma unroll
    for (int ct = 0; ct < 4; ++ct){ accP[rt][ct] = z; accQ[rt][ct] = z; }
  for (int k0 = 0; k0 < 64; k0 += 32){
    bf8v wr[4], wi[4], wn[4];
#pragma unroll
    for (int ct = 0; ct < 4; ++ct){
      int o = (ct << 4) + l15;
      wr[ct] = *(const bf8v*)(Wr + (o << 6) + k0 + (quad << 3));
      wi[ct] = *(const bf8v*)(Wi + (o << 6) + k0 + (quad << 3));
      wn[ct] = bneg(wi[ct]);
    }
#pragma unroll
    for (int rt = 0; rt < 2; ++rt){
      int m = m0 + (rt << 4) + l15;
      bf8v ar = *(const bf8v*)(Xr + (m << 6) + k0 + (quad << 3));
      bf8v ai = *(const bf8v*)(Xi + (m << 6) + k0 + (quad << 3));
#pragma unroll
      for (int ct = 0; ct < 4; ++ct){
        accP[rt][ct] = MFMA16(ar, wr[ct], accP[rt][ct]);
        accP[rt][ct] = MFMA16(ai, wn[ct], accP[rt][ct]);
        accQ[rt][ct] = MFMA16(ar, wi[ct], accQ[rt][ct]);
        accQ[rt][ct] = MFMA16(ai, wr[ct], accQ[rt][ct]);
      }
    }
  }
  u16* Pp = PQ + (((size_t)b * 64 + y) << 14);
  u16* Qp = PQ + (((size_t)b * 64 + 32 + y) << 14);
#pragma unroll
  for (int rt = 0; rt < 2; ++rt)
#pragma unroll
    for (int ct = 0; ct < 4; ++ct)
#pragma unroll
      for (int r = 0; r < 4; ++r){
        int m = m0 + (rt << 4) + (quad << 2) + r;
        int o = (ct << 4) + l15;
        Pp[(m << 6) + o] = f2bf(accP[rt][ct][r]);
        Qp[(m << 6) + o] = f2bf(accQ[rt][ct][r]);
      }
}

// ---------------- K5: inverse-y. per (b,m): g[b][m][n][o] = By(256x64) @ PQy[b][:][m][:]
__global__ __launch_bounds__(256)
void k_inv_y(const u16* __restrict__ PQ, const u16* __restrict__ Bas, u16* __restrict__ g){
  int blk = blockIdx.x, b = blk >> 8, m = blk & 255;
  __shared__ u16 Bld[64][72];   // [o][u]
  int t = threadIdx.x;
  {
    int u = t >> 2, o0 = (t & 3) << 4;
    const u16* p = PQ + (((size_t)b * 64 + u) << 14) + (m << 6) + o0;
    uint4 v0 = *(const uint4*)p;
    uint4 v1 = *(const uint4*)(p + 8);
    u16* d = &Bld[o0][u];
    const u16* e = (const u16*)&v0;
#pragma unroll
    for (int j = 0; j < 8; ++j) d[j * 72] = e[j];
    e = (const u16*)&v1;
#pragma unroll
    for (int j = 0; j < 8; ++j) d[(8 + j) * 72] = e[j];
  }
  __syncthreads();
  int wave = t >> 6, lane = t & 63, quad = lane >> 4, l15 = lane & 15;
  f32x4 z = {0.f, 0.f, 0.f, 0.f};
  f32x4 acc[4][4];
#pragma unroll
  for (int rt = 0; rt < 4; ++rt)
#pragma unroll
    for (int ct = 0; ct < 4; ++ct) acc[rt][ct] = z;
  for (int k0 = 0; k0 < 64; k0 += 32){
    bf8v bb[4];
#pragma unroll
    for (int ct = 0; ct < 4; ++ct)
      bb[ct] = *(const bf8v*)(&Bld[(ct << 4) + l15][k0 + (quad << 3)]);
#pragma unroll
    for (int rt = 0; rt < 4; ++rt){
      int n = (wave << 6) + (rt << 4) + l15;
      bf8v a = *(const bf8v*)(Bas + (n << 6) + k0 + (quad << 3));
#pragma unroll
      for (int ct = 0; ct < 4; ++ct) acc[rt][ct] = MFMA16(a, bb[ct], acc[rt][ct]);
    }
  }
  u16* gp = g + ((size_t)blk << 14);
#pragma unroll
  for (int rt = 0; rt < 4; ++rt)
#pragma unroll
    for (int ct = 0; ct < 4; ++ct)
#pragma unroll
      for (int r = 0; r < 4; ++r){
        int n = (wave << 6) + (rt << 4) + (quad << 2) + r;
        int o = (ct << 4) + l15;
        gp[(n << 6) + o] = f2bf(acc[rt][ct][r]);
      }
}

// ---------------- K6: inverse-x, accumulated into g. per (b,n): Bx(256x64) @ PQx[b][:][n][:]
__global__ __launch_bounds__(256)
void k_inv_x(const u16* __restrict__ PQ, const u16* __restrict__ Bas, u16* __restrict__ g){
  int blk = blockIdx.x, b = blk >> 8, nn = blk & 255;
  __shared__ u16 Bld[64][72];    // [o][u]
  __shared__ u16 ld2[256][72];   // [m][o], bf16
  int t = threadIdx.x;
  {
    int u = t >> 2, o0 = (t & 3) << 4;
    const u16* p = PQ + (((size_t)b * 64 + u) << 14) + (nn << 6) + o0;
    uint4 v0 = *(const uint4*)p;
    uint4 v1 = *(const uint4*)(p + 8);
    u16* d = &Bld[o0][u];
    const u16* e = (const u16*)&v0;
#pragma unroll
    for (int j = 0; j < 8; ++j) d[j * 72] = e[j];
    e = (const u16*)&v1;
#pragma unroll
    for (int j = 0; j < 8; ++j) d[(8 + j) * 72] = e[j];
  }
  __syncthreads();
  int wave = t >> 6, lane = t & 63, quad = lane >> 4, l15 = lane & 15;
  f32x4 z = {0.f, 0.f, 0.f, 0.f};
  f32x4 acc[4][4];
#pragma unroll
  for (int rt = 0; rt < 4; ++rt)
#pragma unroll
    for (int ct = 0; ct < 4; ++ct) acc[rt][ct] = z;
  for (int k0 = 0; k0 < 64; k0 += 32){
    bf8v bb[4];
#pragma unroll
    for (int ct = 0; ct < 4; ++ct)
      bb[ct] = *(const bf8v*)(&Bld[(ct << 4) + l15][k0 + (quad << 3)]);
#pragma unroll
    for (int rt = 0; rt < 4; ++rt){
      int mr = (wave << 6) + (rt << 4) + l15;
      bf8v a = *(const bf8v*)(Bas + (mr << 6) + k0 + (quad << 3));
#pragma unroll
      for (int ct = 0; ct < 4; ++ct) acc[rt][ct] = MFMA16(a, bb[ct], acc[rt][ct]);
    }
  }
#pragma unroll
  for (int rt = 0; rt < 4; ++rt)
#pragma unroll
    for (int ct = 0; ct < 4; ++ct)
#pragma unroll
      for (int r = 0; r < 4; ++r){
        int mr = (wave << 6) + (rt << 4) + (quad << 2) + r;
        ld2[mr][(ct << 4) + l15] = f2bf(acc[rt][ct][r]);
      }
  __syncthreads();
  {
    u16* gp = g + (((size_t)(b * 256 + t)) << 14) + (nn << 6);
    for (int c = 0; c < 8; ++c){
      uint4 v = *(const uint4*)(gp + (c << 3));
      const u16* e = (const u16*)&v;
      u32 wv[4];
#pragma unroll
      for (int jj = 0; jj < 4; ++jj){
        float a0 = bf2f(e[2 * jj])     + bf2f(ld2[t][c * 8 + 2 * jj]);
        float a1 = bf2f(e[2 * jj + 1]) + bf2f(ld2[t][c * 8 + 2 * jj + 1]);
        wv[jj] = (u32)f2bf(a0) | ((u32)f2bf(a1) << 16);
      }
      uint4 nv = {wv[0], wv[1], wv[2], wv[3]};
      *(uint4*)(gp + (c << 3)) = nv;
    }
  }
}

// ---------------- K7 v4: MLP + LayerNorm, column-split, register weights.
// v3 residual: GEMM2's h1 reads were an 8-way bank conflict (row stride
// 512B === 0 mod 128B; 3-bit XOR spread 64 lanes over only 8 slots; 6.3M
// conflict cycles). Fix: 4-bit swizzle col ^ ((row&15)<<4). row&15 == l15
// on BOTH the GEMM1 write (row=(tr<<4)+l15) and GEMM2 read (same), so the
// per-lane XOR term is constant; alignment preserved (writes 4-u16-aligned,
// reads 8-u16-aligned, XOR is 16-u16-granular). Read pattern becomes 32
// distinct 16B chunks / 64 lanes = 2-way = free (m136).
// Also NIT 4->2, grid 4096: more blocks in flight, smoother tail.
#define NIT 2
__global__ __launch_bounds__(256, 3)
void k_mlp(const u16* __restrict__ g, const u16* __restrict__ w1T, const float* __restrict__ b1,
           const u16* __restrict__ w2T, const float* __restrict__ b2,
           const float* __restrict__ gamma, const float* __restrict__ beta,
           float* __restrict__ out){
  __shared__ u16 h1s[64 * 256];      // [row][col ^ ((row&15)<<4)]  32KB
  __shared__ float lnb[2][64][4];    // [sum/ssq][row][wave]       2KB
  int t = threadIdx.x;
  int wave = t >> 6, lane = t & 63, quad = lane >> 4, l15 = lane & 15;
  const int sw4 = l15 << 4;          // == (row&15)<<4 for all rows this lane touches

  // hoisted weight fragments (A-frags of w1 for this wave's 64 h1-cols)
  bf8v w1f[4][2];
#pragma unroll
  for (int ct = 0; ct < 4; ++ct){
    const u16* p = w1T + (((wave << 6) + (ct << 4) + l15) << 6) + (quad << 3);
    w1f[ct][0] = *(const bf8v*)(p);
    w1f[ct][1] = *(const bf8v*)(p + 32);
  }
  // B-frags of w2 for this wave's 16 out-cols (full K=256)
  bf8v w2f[8];
#pragma unroll
  for (int k0 = 0; k0 < 8; ++k0)
    w2f[k0] = *(const bf8v*)(w2T + (((wave << 4) + l15) << 8) + (k0 << 5) + (quad << 3));
  float4 b1c[4];
#pragma unroll
  for (int ct = 0; ct < 4; ++ct)
    b1c[ct] = *(const float4*)(b1 + (wave << 6) + (ct << 4) + (quad << 2));
  int oc = (wave << 4) + l15;
  float b2c = b2[oc], gmc = gamma[oc], btc = beta[oc];
  f32x4 z = {0.f, 0.f, 0.f, 0.f};

  size_t row0 = ((size_t)blockIdx.x * NIT) << 6;
#pragma unroll 1
  for (int it = 0; it < NIT; ++it, row0 += 64){
    // ---- phase 1: GEMM1 (swapped), cols [64w,64w+64) of all 64 rows
#pragma unroll
    for (int tr = 0; tr < 4; ++tr){
      const u16* gA = g + ((row0 + (tr << 4) + l15) << 6) + (quad << 3);
      bf8v a0 = *(const bf8v*)(gA);
      bf8v a1 = *(const bf8v*)(gA + 32);
      int row = (tr << 4) + l15;           // row&15 == l15 -> swizzle == sw4
#pragma unroll
      for (int ct = 0; ct < 4; ++ct){
        f32x4 acc = MFMA16(w1f[ct][0], a0, z);
        acc = MFMA16(w1f[ct][1], a1, acc);
        int c0 = (wave << 6) + (ct << 4) + (quad << 2);
        float4 bv = b1c[ct];
        float v0 = fmaxf(acc[0] + bv.x, 0.f);
        float v1 = fmaxf(acc[1] + bv.y, 0.f);
        float v2 = fmaxf(acc[2] + bv.z, 0.f);
        float v3 = fmaxf(acc[3] + bv.w, 0.f);
        __hip_bfloat162 p0 = __float22bfloat162_rn(make_float2(v0, v1));
        __hip_bfloat162 p1 = __float22bfloat162_rn(make_float2(v2, v3));
        uint2 wv;
        wv.x = *reinterpret_cast<u32*>(&p0);
        wv.y = *reinterpret_cast<u32*>(&p1);
        *(uint2*)(&h1s[(row << 8) + (c0 ^ sw4)]) = wv;
      }
    }
    __syncthreads();   // h1 complete

    // ---- phase 2: GEMM2, all 64 rows x out-cols [16w,16w+16), w2 from regs
    f32x4 acc2[4] = {z, z, z, z};
#pragma unroll
    for (int k0 = 0; k0 < 8; ++k0){
      int koff = (k0 << 5) + (quad << 3);
#pragma unroll
      for (int tr = 0; tr < 4; ++tr){
        bf8v a = *(const bf8v*)(&h1s[(((tr << 4) + l15) << 8) + (koff ^ sw4)]);
        acc2[tr] = MFMA16(a, w2f[k0], acc2[tr]);
      }
    }
    // LN partials over this wave's 16 cols (reduce across l15 lanes)
#pragma unroll
    for (int tr = 0; tr < 4; ++tr){
#pragma unroll
      for (int r = 0; r < 4; ++r){
        float v = acc2[tr][r] + b2c;
        float s = v, q = v * v;
#pragma unroll
        for (int mask = 1; mask < 16; mask <<= 1){
          s += __shfl_xor(s, mask);
          q += __shfl_xor(q, mask);
        }
        if (l15 == 0){
          int row = (tr << 4) + (quad << 2) + r;
          lnb[0][row][wave] = s;
          lnb[1][row][wave] = q;
        }
      }
    }
    __syncthreads();   // partials complete (also guards h1 reuse next iter)

    // ---- phase 3: finish LN + non-temporal store
#pragma unroll
    for (int tr = 0; tr < 4; ++tr){
#pragma unroll
      for (int r = 0; r < 4; ++r){
        int row = (tr << 4) + (quad << 2) + r;
        float4 s4 = *(const float4*)(&lnb[0][row][0]);
        float4 q4 = *(const float4*)(&lnb[1][row][0]);
        float sum = (s4.x + s4.y) + (s4.z + s4.w);
        float ssq = (q4.x + q4.y) + (q4.z + q4.w);
        float mu = sum * 0.015625f;
        float var = ssq * 0.015625f - mu * mu;
        float rs = rsqrtf(var + 1e-5f);
        float v = acc2[tr][r] + b2c;
        __builtin_nontemporal_store((v - mu) * rs * gmc + btc,
                                    out + ((row0 + row) << 6) + oc);
      }
    }
  }
}

extern "C" void kernel_launch(void* const* d_in, const int* in_sizes, int n_in,
                              void* d_out, int out_size, void* d_ws, size_t ws_size,
                              hipStream_t stream){
  const float* x   = (const float*)d_in[0];
  const float* att = (const float*)d_in[1];
  const float* fwy = (const float*)d_in[2];
  const float* fwx = (const float*)d_in[3];
  const float* w1  = (const float*)d_in[4];
  const float* b1  = (const float*)d_in[5];
  const float* w2  = (const float*)d_in[6];
  const float* b2  = (const float*)d_in[7];
  const float* gm  = (const float*)d_in[8];
  const float* bt  = (const float*)d_in[9];
  u16* ws = (u16*)d_ws;
  u16* G   = ws + OFF_G;
  u16* Wy  = ws + OFF_WY;
  u16* Wx  = ws + OFF_WX;
  u16* Xy  = ws + OFF_XY;
  u16* Xx  = ws + OFF_XX;
  u16* PQy = ws + OFF_PQY;
  u16* PQx = ws + OFF_PQX;
  u16* Ey  = ws + OFF_EY;
  u16* Ex  = ws + OFF_EX;
  u16* By  = ws + OFF_BY;
  u16* Bx  = ws + OFF_BX;
  u16* w1T = ws + OFF_W1T;
  u16* w2T = ws + OFF_W2T;

  k_weights<<<dim3(512), dim3(256), 0, stream>>>(att, fwy, fwx, Wy, Wx);
  k_basis<<<dim3(64), dim3(256), 0, stream>>>(Ey, Ex, By, Bx, w1, w2, w1T, w2T);
  k_fwd<<<dim3(4096), dim3(256), 0, stream>>>(x, Ey, Ex, Xy, Xx);
  k_mix<<<dim3(512), dim3(256), 0, stream>>>(Xy, Wy, PQy);
  k_mix<<<dim3(512), dim3(256), 0, stream>>>(Xx, Wx, PQx);
  k_inv_y<<<dim3(2048), dim3(256), 0, stream>>>(PQy, By, G);
  k_inv_x<<<dim3(2048), dim3(256), 0, stream>>>(PQx, Bx, G);
  k_mlp<<<dim3(4096), dim3(256), 0, stream>>>(G, w1T, b1, w2T, b2, gm, bt, (float*)d_out);
}